// Round 15
// baseline (130.059 us; speedup 1.0000x reference)
//
#include <hip/hip_runtime.h>
#include <hip/hip_bf16.h>

// SelfAttentionTransformer: B=4, L=2048, D=256, H=8, dk=32, F=1024
// f32 inputs / f32 output. Round 22:
//  - k_av v4: BK=128 (16 K-steps, half the barriers/waits), 64x64 tiles,
//    512 blocks, 2-deep x 36 KB = 72 KB -> 2 blocks/CU (4 waves/SIMD kept).
//    mod-16 granule rotation (<=2-way banks). K-order identical (bit-exact).
//  - k_prep v2 / k_scores / k_ffn v3 unchanged (R21 = 127.5 us baseline).

#define B_ 4
#define L_ 2048
#define D_ 256
#define F_ 1024
#define PI_F 3.14159265358979323846f

typedef __bf16 bf16x8 __attribute__((ext_vector_type(8)));
typedef float floatx4 __attribute__((ext_vector_type(4)));
typedef unsigned short ushortx4 __attribute__((ext_vector_type(4)));
typedef unsigned short ushortx8 __attribute__((ext_vector_type(8)));

#define WAIT_VM(n) asm volatile("s_waitcnt vmcnt(" #n ")" ::: "memory")
#define WAIT_LGKM() asm volatile("s_waitcnt lgkmcnt(0)" ::: "memory")
#define SCHED0() __builtin_amdgcn_sched_barrier(0)
#define BARRIER() do { SCHED0(); __builtin_amdgcn_s_barrier(); SCHED0(); } while (0)

__device__ __forceinline__ unsigned short f2bf(float f) {
    unsigned int u = __float_as_uint(f);
    u = (u + 0x7FFFu + ((u >> 16) & 1u)) >> 16;   // RNE
    return (unsigned short)u;
}
__device__ __forceinline__ float bf2f(unsigned short u) {
    union { unsigned int i; float f; } v; v.i = ((unsigned int)u) << 16; return v.f;
}

__device__ __forceinline__ void async_cp16(unsigned short* lds, const unsigned short* g) {
    __builtin_amdgcn_global_load_lds(
        (const __attribute__((address_space(1))) unsigned int*)g,
        (__attribute__((address_space(3))) unsigned int*)lds, 16, 0, 0);
}

// ---------------- prep v2, compact 1D grid (1537 blocks) ----------------
__global__ __launch_bounds__(256) void k_prep(const float* __restrict__ x,
                                              const float* __restrict__ W1,
                                              const float* __restrict__ W2,
                                              const int* __restrict__ mask,
                                              unsigned short* __restrict__ mb,
                                              unsigned short* __restrict__ XmT,
                                              unsigned short* __restrict__ W1T,
                                              unsigned short* __restrict__ W2T) {
    __shared__ float ldsT[32 * 65];   // [col][row], pad 65 -> <=2-way banks
    __shared__ float msk[64];
    int r = blockIdx.x, t = threadIdx.x;
    if (r >= 1280) {
        if (r < 1536) {
            int idx = (r - 1280) * 256 + t;   // 0..65535
            int l = idx >> 5, k = idx & 31;
            float s = 0.f;
#pragma unroll
            for (int b = 0; b < B_; b++) {
                const float* xp = x + ((size_t)(b * L_ + l)) * D_ + k;
#pragma unroll
                for (int h = 0; h < 8; h++) s += xp[h * 32];
            }
            mb[idx] = f2bf(s * (1.f / 32.f));
        } else {
#pragma unroll
            for (int c = 0; c < 32; c++) {
                int e = c * 256 + t;          // 0..8191
                int b = e >> 11, j = e & (L_ - 1);
                XmT[(size_t)(1024 + b) * L_ + j] = mask[b * L_ + j] ? 0x3F80 : 0;
            }
        }
        return;
    }
    const float* in; unsigned short* outp; int R, C; const int* mrow = nullptr; size_t bo = 0;
    int rt, cb;
    if (r < 1024) {
        int z = r >> 8, rem = r & 255;        // 32 rt x 8 cb
        rt = rem >> 3; cb = rem & 7;
        in = x; outp = XmT; R = L_; C = 256; bo = (size_t)z * R * C;
        mrow = mask + z * L_;
    } else if (r < 1152) {
        int rem = r - 1024; rt = rem >> 5; cb = rem & 31;   // 4 x 32
        in = W1; outp = W1T; R = 256; C = 1024;
    } else {
        int rem = r - 1152; rt = rem >> 3; cb = rem & 7;    // 16 x 8
        in = W2; outp = W2T; R = 1024; C = 256;
    }
    int r0 = rt * 64, c0 = cb * 32;
    if (mrow && t < 64) msk[t] = mrow[r0 + t] ? 1.f : 0.f;
#pragma unroll
    for (int k = 0; k < 2; k++) {
        int q = t + k * 256;              // 0..511
        int row = q >> 3, cq = q & 7;     // 64 rows x 8 col-quads
        float4 v = *(const float4*)(in + bo + (size_t)(r0 + row) * C + c0 + cq * 4);
        ldsT[(cq * 4 + 0) * 65 + row] = v.x;
        ldsT[(cq * 4 + 1) * 65 + row] = v.y;
        ldsT[(cq * 4 + 2) * 65 + row] = v.z;
        ldsT[(cq * 4 + 3) * 65 + row] = v.w;
    }
    __syncthreads();
#pragma unroll
    for (int k = 0; k < 2; k++) {
        int q = t + k * 256;              // 0..511
        int c = q >> 4, rq = q & 15;      // 32 out-rows x 16 quads
        float f0 = ldsT[c * 65 + rq * 4 + 0];
        float f1 = ldsT[c * 65 + rq * 4 + 1];
        float f2 = ldsT[c * 65 + rq * 4 + 2];
        float f3 = ldsT[c * 65 + rq * 4 + 3];
        if (mrow) {
            f0 *= msk[rq * 4 + 0];
            f1 *= msk[rq * 4 + 1];
            f2 *= msk[rq * 4 + 2];
            f3 *= msk[rq * 4 + 3];
        }
        ushortx4 o;
        o.x = f2bf(f0); o.y = f2bf(f1); o.z = f2bf(f2); o.w = f2bf(f3);
        *(ushortx4*)(outp + bo + (size_t)(c0 + c) * R + r0 + rq * 4) = o;
    }
}

// ---------------- E = exp(sin^2(0.5*clip(m.mT))) via MFMA, bf16 out ----------------
__global__ __launch_bounds__(256) void k_scores_mfma(const unsigned short* __restrict__ mb,
                                                     unsigned short* __restrict__ E) {
    const int t = threadIdx.x, lane = t & 63, wid = t >> 6;
    const int wm = (wid >> 1) * 64, wn = (wid & 1) * 32;
    const int lr = lane & 15, lq = lane >> 4;
    int m0 = blockIdx.y * 128, n0 = blockIdx.x * 64;
    bf16x8 af[4], bfr[2];
#pragma unroll
    for (int i = 0; i < 4; i++)
        af[i] = *(const bf16x8*)(mb + (size_t)(m0 + wm + i * 16 + lr) * 32 + lq * 8);
#pragma unroll
    for (int j = 0; j < 2; j++)
        bfr[j] = *(const bf16x8*)(mb + (size_t)(n0 + wn + j * 16 + lr) * 32 + lq * 8);
    floatx4 acc[4][2];
#pragma unroll
    for (int i = 0; i < 4; i++)
#pragma unroll
        for (int j = 0; j < 2; j++) {
            acc[i][j] = (floatx4){0.f, 0.f, 0.f, 0.f};
            acc[i][j] = __builtin_amdgcn_mfma_f32_16x16x32_bf16(af[i], bfr[j], acc[i][j], 0, 0, 0);
        }
#pragma unroll
    for (int i = 0; i < 4; i++)
#pragma unroll
        for (int j = 0; j < 2; j++)
#pragma unroll
            for (int r = 0; r < 4; r++) {
                int row = m0 + wm + i * 16 + lq * 4 + r;
                int col = n0 + wn + j * 16 + lr;
                float d = fminf(fmaxf(acc[i][j][r], -PI_F), PI_F);
                float sn = __sinf(0.5f * d);
                E[(size_t)row * L_ + col] = f2bf(__expf(sn * sn));
            }
}

// ---------------- AV v4: C[2048,1024] = E @ XmT^T (bf16) + rowsums
//                  64x64 tiles, BK=128 (16 steps), 512 blocks, 2-deep ----------------
__global__ __launch_bounds__(512) void k_av(const unsigned short* __restrict__ E,
                                            const unsigned short* __restrict__ XmT,
                                            unsigned short* __restrict__ Cb,
                                            float* __restrict__ rs) {
    // 2 buffers x (64x128 A + 64x128 B + 16x128 M) bf16 = 2 x 36 KB = 72 KB
    __shared__ __align__(16) unsigned short sbuf[2][(64 + 64 + 16) * 128];
    const int t = threadIdx.x, lane = t & 63, wid = t >> 6;      // wid 0..7
    const int wm = (wid >> 1) * 16, wn = (wid & 1) * 32;         // 4M x 2N wave grid
    const int lr = lane & 15, lq = lane >> 4;
    const int lrow4 = lane >> 4, lg = lane & 15;                 // staging: 4 rows x 16 granules

    // bijective XCD swizzle: 512 = 8 * 64
    int bid = blockIdx.x;
    int swz = (bid & 7) * 64 + (bid >> 3);
    int m0 = (swz >> 4) * 64, n0 = (swz & 15) * 64;
    const bool doMask = (n0 == 0);
    const bool maskw = doMask && ((wid & 1) == 0);   // wn==0 waves compute rowsums
    const bool mload = doMask && (wid < 2);          // waves 0-1 stage 16 M rows

    // A staging: wave stages 8 rows (2 insts x 4 rows x 16 granules)
    const unsigned short* Ag[2]; int sAoff[2];
    const unsigned short* Bg[2]; int sBoff[2];
    const unsigned short* Mg[2]; int sMoff[2];
#pragma unroll
    for (int q = 0; q < 2; q++) {
        int rl = wid * 8 + q * 4 + lrow4;
        Ag[q] = E + (size_t)(m0 + rl) * L_ + ((lg - rl) & 15) * 8;
        sAoff[q] = (wid * 8 + q * 4) * 128;
        Bg[q] = XmT + (size_t)(n0 + rl) * L_ + ((lg - rl) & 15) * 8;
        sBoff[q] = 8192 + (wid * 8 + q * 4) * 128;
        Mg[q] = XmT + (size_t)(1024 + rl) * L_ + ((lg - rl) & 15) * 8;
        sMoff[q] = 16384 + (wid * 8 + q * 4) * 128;
    }

    const int aroff = (wm + lr) * 128, arot = lq + wm + lr;
    int broff[2], brot[2];
#pragma unroll
    for (int j = 0; j < 2; j++) { int br = wn + j * 16 + lr; broff[j] = 8192 + br * 128; brot[j] = lq + br; }
    const int mroff = 16384 + lr * 128, mrot = lq + lr;

    floatx4 acc[2], acc3;
#pragma unroll
    for (int j = 0; j < 2; j++) acc[j] = (floatx4){0.f, 0.f, 0.f, 0.f};
    acc3 = (floatx4){0.f, 0.f, 0.f, 0.f};

    auto stage = [&](unsigned short* base, int k0) {
#pragma unroll
        for (int q = 0; q < 2; q++) {
            async_cp16(base + sAoff[q], Ag[q] + k0);
            async_cp16(base + sBoff[q], Bg[q] + k0);
        }
        if (mload) {
#pragma unroll
            for (int q = 0; q < 2; q++) async_cp16(base + sMoff[q], Mg[q] + k0);
        }
    };
    auto compute = [&](const unsigned short* base) {
#pragma unroll
        for (int s = 0; s < 4; s++) {
            bf16x8 af = *(const bf16x8*)(base + aroff + ((s * 4 + arot) & 15) * 8);
#pragma unroll
            for (int j = 0; j < 2; j++) {
                bf16x8 bfr = *(const bf16x8*)(base + broff[j] + ((s * 4 + brot[j]) & 15) * 8);
                acc[j] = __builtin_amdgcn_mfma_f32_16x16x32_bf16(af, bfr, acc[j], 0, 0, 0);
            }
            if (maskw) {
                bf16x8 bm = *(const bf16x8*)(base + mroff + ((s * 4 + mrot) & 15) * 8);
                acc3 = __builtin_amdgcn_mfma_f32_16x16x32_bf16(af, bm, acc3, 0, 0, 0);
            }
        }
    };

    unsigned short *p0 = sbuf[0], *p1 = sbuf[1];
    stage(p0, 0); stage(p1, 128);
    if (mload) { WAIT_VM(6); } else { WAIT_VM(4); }   // step0 landed
    BARRIER();
    for (int p = 0; p < 14; ++p) {
        compute(p0);
        BARRIER();                          // done reading p0
        stage(p0, (p + 2) << 7);
        if (mload) { WAIT_VM(6); } else { WAIT_VM(4); }   // step p+1 landed
        BARRIER();
        unsigned short* tmp = p0; p0 = p1; p1 = tmp;
    }
    compute(p0);                            // step 14
    BARRIER();
    WAIT_VM(0); BARRIER();                  // step 15 landed
    compute(p1);                            // step 15

#pragma unroll
    for (int j = 0; j < 2; j++)
#pragma unroll
        for (int r = 0; r < 4; r++) {
            int row = m0 + wm + lq * 4 + r;
            int col = n0 + wn + j * 16 + lr;
            Cb[(size_t)row * 1024 + col] = f2bf(acc[j][r]);
        }
    if (maskw && lr < 4) {
#pragma unroll
        for (int r = 0; r < 4; r++) {
            int row = m0 + wm + lq * 4 + r;
            rs[(size_t)row * 4 + lr] = acc3[r];
        }
    }
}

// ---------------- k_ffn v3: producer-consumer, 512 threads ----------------
__global__ __launch_bounds__(512, 1) void k_ffn(const float* __restrict__ x,
                                                const unsigned short* __restrict__ Cb,
                                                const float* __restrict__ rs,
                                                const unsigned short* __restrict__ W1T,
                                                const unsigned short* __restrict__ W2T,
                                                const float* __restrict__ b1,
                                                const float* __restrict__ b2,
                                                const float* __restrict__ g1, const float* __restrict__ be1,
                                                const float* __restrict__ g2, const float* __restrict__ be2,
                                                float* __restrict__ out) {
    __shared__ __align__(16) unsigned short hA[4 * 32 * 64];        // 16 KB
    __shared__ __align__(16) unsigned short W1b[2][4 * 64 * 64];    // 64 KB
    __shared__ __align__(16) unsigned short W2b[2][4 * 64 * 64];    // 64 KB
    __shared__ __align__(16) unsigned short t1c[2][32 * 72];        // 9 KB
    __shared__ float b1s[1024];                                     // 4 KB
    __shared__ float red[4][32][2];                                 // 1 KB  => 158 KB

    const int t = threadIdx.x, lane = t & 63, wid = t >> 6;
    const bool isG1 = wid < 4;
    const int gw = wid & 3;
    const int lr = lane & 15, lq = lane >> 4;
    const int half = lane >> 5, l32 = lane & 31;
    const int lrow8 = lane >> 3, kk = lane & 7;
    const int m0 = blockIdx.x * 32;

    auto stageW1 = [&](unsigned short* buf, int fc) {
#pragma unroll
        for (int q = 0; q < 8; q++) {
            int kc = q >> 1, sub = q & 1;
            int fl = sub * 32 + gw * 8 + lrow8;
            const unsigned short* src = W1T + (size_t)(fc * 64 + fl) * 256 + kc * 64 + (((kk - fl) & 7) * 8);
            async_cp16(buf + kc * 4096 + sub * 2048 + gw * 512, src);
        }
    };
    auto stageW2 = [&](unsigned short* buf, int fc) {
#pragma unroll
        for (int q = 0; q < 8; q++) {
            int nc = q >> 1, sub = q & 1;
            int nl = sub * 32 + gw * 8 + lrow8;
            const unsigned short* src = W2T + (size_t)(nc * 64 + nl) * 1024 + fc * 64 + (((kk - nl) & 7) * 8);
            async_cp16(buf + nc * 4096 + sub * 2048 + gw * 512, src);
        }
    };

    if (isG1) { stageW1(W1b[0], 0); stageW1(W1b[1], 1); }
    else      { stageW2(W2b[0], 0); stageW2(W2b[1], 1); }

    b1s[t] = b1[t];
    b1s[512 + t] = b1[512 + t];
    float4 g1a = *(const float4*)(g1 + l32 * 8);
    float4 g1b = *(const float4*)(g1 + l32 * 8 + 4);
    float4 be1a = *(const float4*)(be1 + l32 * 8);
    float4 be1b = *(const float4*)(be1 + l32 * 8 + 4);

    // ---- LN1: h[32][256] -> hA (rotate-swizzled), 4 tokens/wave ----
#pragma unroll
    for (int it = 0; it < 2; it++) {
        int tloc = wid * 4 + it * 2 + half;
        int tok = m0 + tloc;
        int bi = tok >> 11, ii = tok & (L_ - 1);
        float rsv = rs[(size_t)ii * 4 + bi];
        float4 xv0 = *(const float4*)(x + (size_t)tok * D_ + l32 * 8);
        float4 xv1 = *(const float4*)(x + (size_t)tok * D_ + l32 * 8 + 4);
        ushortx8 cv = *(const ushortx8*)(Cb + (size_t)ii * 1024 + bi * 256 + l32 * 8);
        float v[8];
        v[0] = xv0.x + bf2f(cv[0]) / rsv; v[1] = xv0.y + bf2f(cv[1]) / rsv;
        v[2] = xv0.z + bf2f(cv[2]) / rsv; v[3] = xv0.w + bf2f(cv[3]) / rsv;
        v[4] = xv1.x + bf2f(cv[4]) / rsv; v[5] = xv1.y + bf2f(cv[5]) / rsv;
        v[6] = xv1.z + bf2f(cv[6]) / rsv; v[7] = xv1.w + bf2f(cv[7]) / rsv;
        float s = 0.f, s2 = 0.f;
#pragma unroll
        for (int k = 0; k < 8; k++) { s += v[k]; s2 += v[k] * v[k]; }
#pragma unroll
        for (int o = 1; o < 32; o <<= 1) { s += __shfl_xor(s, o); s2 += __shfl_xor(s2, o); }
        float mu = s * (1.f / 256.f);
        float var = s2 * (1.f / 256.f) - mu * mu;
        float rq = rsqrtf(var + 1e-5f);
        union { bf16x8 v8; unsigned short u[8]; } hv;
        hv.u[0] = f2bf((v[0] - mu) * rq * g1a.x + be1a.x);
        hv.u[1] = f2bf((v[1] - mu) * rq * g1a.y + be1a.y);
        hv.u[2] = f2bf((v[2] - mu) * rq * g1a.z + be1a.z);
        hv.u[3] = f2bf((v[3] - mu) * rq * g1a.w + be1a.w);
        hv.u[4] = f2bf((v[4] - mu) * rq * g1b.x + be1b.x);
        hv.u[5] = f2bf((v[5] - mu) * rq * g1b.y + be1b.y);
        hv.u[6] = f2bf((v[6] - mu) * rq * g1b.z + be1b.z);
        hv.u[7] = f2bf((v[7] - mu) * rq * g1b.w + be1b.w);
        *(bf16x8*)(hA + (l32 >> 3) * 2048 + tloc * 64 + ((((l32 & 7) + tloc) & 7) * 8)) = hv.v8;
    }
    WAIT_VM(0); WAIT_LGKM(); BARRIER();

    bf16x8 haf[2][8];
    if (isG1) {
#pragma unroll
        for (int i = 0; i < 2; i++)
#pragma unroll
            for (int kc = 0; kc < 4; kc++)
#pragma unroll
                for (int s = 0; s < 2; s++) {
                    int row = i * 16 + lr;
                    haf[i][kc * 2 + s] = *(const bf16x8*)(hA + kc * 2048 + row * 64 + (((s * 4 + lq + row) & 7) * 8));
                }
    }

    floatx4 acc[2][4];
#pragma unroll
    for (int i = 0; i < 2; i++)
#pragma unroll
        for (int j = 0; j < 4; j++) acc[i][j] = (floatx4){0.f, 0.f, 0.f, 0.f};

    const int wcol = gw * 16 + lr;

#pragma unroll 1
    for (int cc = 0; cc <= 16; ++cc) {
        if (cc >= 15) { WAIT_VM(0); } else { WAIT_VM(8); }
        BARRIER();
        if (isG1) {
            if (cc < 16) {
                const unsigned short* w1cur = W1b[cc & 1];
                floatx4 a1[2] = { (floatx4){0.f,0.f,0.f,0.f}, (floatx4){0.f,0.f,0.f,0.f} };
#pragma unroll
                for (int kc = 0; kc < 4; kc++)
#pragma unroll
                    for (int s = 0; s < 2; s++) {
                        bf16x8 bfr = *(const bf16x8*)(w1cur + kc * 4096 + wcol * 64 + (((s * 4 + lq + wcol) & 7) * 8));
                        a1[0] = __builtin_amdgcn_mfma_f32_16x16x32_bf16(haf[0][kc * 2 + s], bfr, a1[0], 0, 0, 0);
                        a1[1] = __builtin_amdgcn_mfma_f32_16x16x32_bf16(haf[1][kc * 2 + s], bfr, a1[1], 0, 0, 0);
                    }
                float bv = b1s[cc * 64 + wcol];
                unsigned short* tc = t1c[cc & 1];
#pragma unroll
                for (int i = 0; i < 2; i++)
#pragma unroll
                    for (int r = 0; r < 4; r++)
                        tc[(i * 16 + lq * 4 + r) * 72 + wcol] = f2bf(fmaxf(a1[i][r] + bv, 0.f));
                WAIT_LGKM();
            }
        } else {
            if (cc >= 1) {
                int d = cc - 1;
                const unsigned short* w2cur = W2b[d & 1];
                const unsigned short* tc = t1c[d & 1];
#pragma unroll
                for (int s = 0; s < 2; s++) {
                    bf16x8 af0 = *(const bf16x8*)(tc + lr * 72 + s * 32 + lq * 8);
                    bf16x8 af1 = *(const bf16x8*)(tc + (16 + lr) * 72 + s * 32 + lq * 8);
#pragma unroll
                    for (int j = 0; j < 4; j++) {
                        int nl = j * 16 + lr;
                        bf16x8 bfr = *(const bf16x8*)(w2cur + gw * 4096 + nl * 64 + (((s * 4 + lq + nl) & 7) * 8));
                        acc[0][j] = __builtin_amdgcn_mfma_f32_16x16x32_bf16(af0, bfr, acc[0][j], 0, 0, 0);
                        acc[1][j] = __builtin_amdgcn_mfma_f32_16x16x32_bf16(af1, bfr, acc[1][j], 0, 0, 0);
                    }
                }
            }
        }
        BARRIER();
        if (isG1) {
            if (cc <= 13) stageW1(W1b[cc & 1], cc + 2);
        } else {
            if (cc >= 1 && cc <= 14) stageW2(W2b[(cc - 1) & 1], cc + 1);
        }
    }

    // ---- LN2 epilogue (G2) ----
    float psum[2][4], psq[2][4];
#pragma unroll
    for (int i = 0; i < 2; i++)
#pragma unroll
        for (int r = 0; r < 4; r++) { psum[i][r] = 0.f; psq[i][r] = 0.f; }
    if (!isG1) {
#pragma unroll
        for (int i = 0; i < 2; i++)
#pragma unroll
            for (int j = 0; j < 4; j++) {
                int col = gw * 64 + j * 16 + lr;
                float bv = b2[col];
                int kc = col >> 6, ks = (col >> 3) & 7, ke = col & 7;
#pragma unroll
                for (int r = 0; r < 4; r++) {
                    int row = i * 16 + lq * 4 + r;
                    float hres = bf2f(hA[kc * 2048 + row * 64 + (((ks + row) & 7) * 8) + ke]);
                    float v = acc[i][j][r] + bv + hres;
                    acc[i][j][r] = v;
                    psum[i][r] += v; psq[i][r] += v * v;
                }
            }
#pragma unroll
        for (int o = 1; o < 16; o <<= 1)
#pragma unroll
            for (int i = 0; i < 2; i++)
#pragma unroll
                for (int r = 0; r < 4; r++) { psum[i][r] += __shfl_xor(psum[i][r], o); psq[i][r] += __shfl_xor(psq[i][r], o); }
        if (lr == 0) {
#pragma unroll
            for (int i = 0; i < 2; i++)
#pragma unroll
                for (int r = 0; r < 4; r++) {
                    int lrow = i * 16 + lq * 4 + r;
                    red[gw][lrow][0] = psum[i][r];
                    red[gw][lrow][1] = psq[i][r];
                }
        }
    }
    __syncthreads();
    if (!isG1) {
#pragma unroll
        for (int i = 0; i < 2; i++)
#pragma unroll
            for (int r = 0; r < 4; r++) {
                int lrow = i * 16 + lq * 4 + r;
                float s  = red[0][lrow][0] + red[1][lrow][0] + red[2][lrow][0] + red[3][lrow][0];
                float s2 = red[0][lrow][1] + red[1][lrow][1] + red[2][lrow][1] + red[3][lrow][1];
                float mu = s * (1.f / 256.f);
                float var = s2 * (1.f / 256.f) - mu * mu;
                float rc = rsqrtf(var + 1e-5f);
                int row = m0 + lrow;
#pragma unroll
                for (int j = 0; j < 4; j++) {
                    int col = gw * 64 + j * 16 + lr;
                    out[(size_t)row * 256 + col] = (acc[i][j][r] - mu) * rc * g2[col] + be2[col];
                }
            }
    }
}

extern "C" void kernel_launch(void* const* d_in, const int* in_sizes, int n_in,
                              void* d_out, int out_size, void* d_ws, size_t ws_size,
                              hipStream_t stream) {
    const float* x   = (const float*)d_in[0];
    const int*  mask = (const int*)d_in[1];
    const float* W1  = (const float*)d_in[2];
    const float* b1  = (const float*)d_in[3];
    const float* W2  = (const float*)d_in[4];
    const float* b2  = (const float*)d_in[5];
    const float* g1  = (const float*)d_in[6];
    const float* be1 = (const float*)d_in[7];
    const float* g2  = (const float*)d_in[8];
    const float* be2 = (const float*)d_in[9];
    float* out = (float*)d_out;

    char* w = (char*)d_ws;
    unsigned short* mb_   = (unsigned short*)w;  w += 65536 * 2;                 // 128 KB
    unsigned short* E_    = (unsigned short*)w;  w += (size_t)L_ * L_ * 2;       // 8 MB
    unsigned short* XmT_  = (unsigned short*)w;  w += (size_t)1088 * L_ * 2;     // 4.25 MB (rows 0..1039 read)
    unsigned short* W1T_  = (unsigned short*)w;  w += 262144 * 2;                // 512 KB
    unsigned short* W2T_  = (unsigned short*)w;  w += 262144 * 2;                // 512 KB
    unsigned short* Cb_   = (unsigned short*)w;  w += (size_t)L_ * 1024 * 2;     // 4 MB
    float*          rs_   = (float*)w;           w += (size_t)L_ * 4 * 4;        // 32 KB

    k_prep<<<1537, 256, 0, stream>>>(x, W1, W2, mask, mb_, XmT_, W1T_, W2T_);
    k_scores_mfma<<<dim3(32, 16), 256, 0, stream>>>(mb_, E_);
    k_av<<<512, 512, 0, stream>>>(E_, XmT_, Cb_, rs_);
    k_ffn<<<256, 512, 0, stream>>>(x, Cb_, rs_, W1T_, W2T_, b1, b2, g1, be1, g2, be2, out);
}

// Round 16
// 126.393 us; speedup vs baseline: 1.0290x; 1.0290x over previous
//
#include <hip/hip_runtime.h>
#include <hip/hip_bf16.h>

// SelfAttentionTransformer: B=4, L=2048, D=256, H=8, dk=32, F=1024
// f32 inputs / f32 output. Round 23 = exact revert to Round 21 (session best,
// 127.5 us). R22's BK=128 regressed (+2.6: 2-deep halved prefetch distance;
// m132 lesson confirmed). Final configuration:
//  - k_prep v2: vectorized 64x32 transposes, LDS [col][row] pad-65
//  - k_scores: single-MFMA 128x64 tiles, sin/exp epilogue
//  - k_av v3: 64x64 tiles, 512 blocks (2/CU -> 4 waves/SIMD), 8 waves,
//    3-deep counted-vmcnt, rowsums folded via mask B-frag (f32-exact)
//  - k_ffn v3: producer-consumer wave specialization (G1 GEMM1 / G2 GEMM2+LN2),
//    counted vmcnt, 2-ahead weight staging

#define B_ 4
#define L_ 2048
#define D_ 256
#define F_ 1024
#define PI_F 3.14159265358979323846f

typedef __bf16 bf16x8 __attribute__((ext_vector_type(8)));
typedef float floatx4 __attribute__((ext_vector_type(4)));
typedef unsigned short ushortx4 __attribute__((ext_vector_type(4)));
typedef unsigned short ushortx8 __attribute__((ext_vector_type(8)));

#define WAIT_VM(n) asm volatile("s_waitcnt vmcnt(" #n ")" ::: "memory")
#define WAIT_LGKM() asm volatile("s_waitcnt lgkmcnt(0)" ::: "memory")
#define SCHED0() __builtin_amdgcn_sched_barrier(0)
#define BARRIER() do { SCHED0(); __builtin_amdgcn_s_barrier(); SCHED0(); } while (0)

__device__ __forceinline__ unsigned short f2bf(float f) {
    unsigned int u = __float_as_uint(f);
    u = (u + 0x7FFFu + ((u >> 16) & 1u)) >> 16;   // RNE
    return (unsigned short)u;
}
__device__ __forceinline__ float bf2f(unsigned short u) {
    union { unsigned int i; float f; } v; v.i = ((unsigned int)u) << 16; return v.f;
}

__device__ __forceinline__ void async_cp16(unsigned short* lds, const unsigned short* g) {
    __builtin_amdgcn_global_load_lds(
        (const __attribute__((address_space(1))) unsigned int*)g,
        (__attribute__((address_space(3))) unsigned int*)lds, 16, 0, 0);
}

// ---------------- prep v2, compact 1D grid (1537 blocks) ----------------
__global__ __launch_bounds__(256) void k_prep(const float* __restrict__ x,
                                              const float* __restrict__ W1,
                                              const float* __restrict__ W2,
                                              const int* __restrict__ mask,
                                              unsigned short* __restrict__ mb,
                                              unsigned short* __restrict__ XmT,
                                              unsigned short* __restrict__ W1T,
                                              unsigned short* __restrict__ W2T) {
    __shared__ float ldsT[32 * 65];   // [col][row], pad 65 -> <=2-way banks
    __shared__ float msk[64];
    int r = blockIdx.x, t = threadIdx.x;
    if (r >= 1280) {
        if (r < 1536) {
            int idx = (r - 1280) * 256 + t;   // 0..65535
            int l = idx >> 5, k = idx & 31;
            float s = 0.f;
#pragma unroll
            for (int b = 0; b < B_; b++) {
                const float* xp = x + ((size_t)(b * L_ + l)) * D_ + k;
#pragma unroll
                for (int h = 0; h < 8; h++) s += xp[h * 32];
            }
            mb[idx] = f2bf(s * (1.f / 32.f));
        } else {
#pragma unroll
            for (int c = 0; c < 32; c++) {
                int e = c * 256 + t;          // 0..8191
                int b = e >> 11, j = e & (L_ - 1);
                XmT[(size_t)(1024 + b) * L_ + j] = mask[b * L_ + j] ? 0x3F80 : 0;
            }
        }
        return;
    }
    const float* in; unsigned short* outp; int R, C; const int* mrow = nullptr; size_t bo = 0;
    int rt, cb;
    if (r < 1024) {
        int z = r >> 8, rem = r & 255;        // 32 rt x 8 cb
        rt = rem >> 3; cb = rem & 7;
        in = x; outp = XmT; R = L_; C = 256; bo = (size_t)z * R * C;
        mrow = mask + z * L_;
    } else if (r < 1152) {
        int rem = r - 1024; rt = rem >> 5; cb = rem & 31;   // 4 x 32
        in = W1; outp = W1T; R = 256; C = 1024;
    } else {
        int rem = r - 1152; rt = rem >> 3; cb = rem & 7;    // 16 x 8
        in = W2; outp = W2T; R = 1024; C = 256;
    }
    int r0 = rt * 64, c0 = cb * 32;
    if (mrow && t < 64) msk[t] = mrow[r0 + t] ? 1.f : 0.f;
#pragma unroll
    for (int k = 0; k < 2; k++) {
        int q = t + k * 256;              // 0..511
        int row = q >> 3, cq = q & 7;     // 64 rows x 8 col-quads
        float4 v = *(const float4*)(in + bo + (size_t)(r0 + row) * C + c0 + cq * 4);
        ldsT[(cq * 4 + 0) * 65 + row] = v.x;
        ldsT[(cq * 4 + 1) * 65 + row] = v.y;
        ldsT[(cq * 4 + 2) * 65 + row] = v.z;
        ldsT[(cq * 4 + 3) * 65 + row] = v.w;
    }
    __syncthreads();
#pragma unroll
    for (int k = 0; k < 2; k++) {
        int q = t + k * 256;              // 0..511
        int c = q >> 4, rq = q & 15;      // 32 out-rows x 16 quads
        float f0 = ldsT[c * 65 + rq * 4 + 0];
        float f1 = ldsT[c * 65 + rq * 4 + 1];
        float f2 = ldsT[c * 65 + rq * 4 + 2];
        float f3 = ldsT[c * 65 + rq * 4 + 3];
        if (mrow) {
            f0 *= msk[rq * 4 + 0];
            f1 *= msk[rq * 4 + 1];
            f2 *= msk[rq * 4 + 2];
            f3 *= msk[rq * 4 + 3];
        }
        ushortx4 o;
        o.x = f2bf(f0); o.y = f2bf(f1); o.z = f2bf(f2); o.w = f2bf(f3);
        *(ushortx4*)(outp + bo + (size_t)(c0 + c) * R + r0 + rq * 4) = o;
    }
}

// ---------------- E = exp(sin^2(0.5*clip(m.mT))) via MFMA, bf16 out ----------------
__global__ __launch_bounds__(256) void k_scores_mfma(const unsigned short* __restrict__ mb,
                                                     unsigned short* __restrict__ E) {
    const int t = threadIdx.x, lane = t & 63, wid = t >> 6;
    const int wm = (wid >> 1) * 64, wn = (wid & 1) * 32;
    const int lr = lane & 15, lq = lane >> 4;
    int m0 = blockIdx.y * 128, n0 = blockIdx.x * 64;
    bf16x8 af[4], bfr[2];
#pragma unroll
    for (int i = 0; i < 4; i++)
        af[i] = *(const bf16x8*)(mb + (size_t)(m0 + wm + i * 16 + lr) * 32 + lq * 8);
#pragma unroll
    for (int j = 0; j < 2; j++)
        bfr[j] = *(const bf16x8*)(mb + (size_t)(n0 + wn + j * 16 + lr) * 32 + lq * 8);
    floatx4 acc[4][2];
#pragma unroll
    for (int i = 0; i < 4; i++)
#pragma unroll
        for (int j = 0; j < 2; j++) {
            acc[i][j] = (floatx4){0.f, 0.f, 0.f, 0.f};
            acc[i][j] = __builtin_amdgcn_mfma_f32_16x16x32_bf16(af[i], bfr[j], acc[i][j], 0, 0, 0);
        }
#pragma unroll
    for (int i = 0; i < 4; i++)
#pragma unroll
        for (int j = 0; j < 2; j++)
#pragma unroll
            for (int r = 0; r < 4; r++) {
                int row = m0 + wm + i * 16 + lq * 4 + r;
                int col = n0 + wn + j * 16 + lr;
                float d = fminf(fmaxf(acc[i][j][r], -PI_F), PI_F);
                float sn = __sinf(0.5f * d);
                E[(size_t)row * L_ + col] = f2bf(__expf(sn * sn));
            }
}

// ---------------- AV v3: C[2048,1024] = E @ XmT^T (bf16) + rowsums
//                  64x64 tiles, 512 blocks (2/CU), 8 waves, 3-deep counted ----------------
__global__ __launch_bounds__(512) void k_av(const unsigned short* __restrict__ E,
                                            const unsigned short* __restrict__ XmT,
                                            unsigned short* __restrict__ Cb,
                                            float* __restrict__ rs) {
    // 3 buffers x (64x64 A + 64x64 B + 16x64 M) = 3 x 9216 elems = 54 KB
    __shared__ __align__(16) unsigned short sbuf[3][64 * 64 + 64 * 64 + 16 * 64];
    const int t = threadIdx.x, lane = t & 63, wid = t >> 6;      // wid 0..7
    const int wm = (wid >> 1) * 16, wn = (wid & 1) * 32;         // 4M x 2N wave grid
    const int lr = lane & 15, lq = lane >> 4;
    const int lrow = lane >> 3, lseg = lane & 7;

    // bijective XCD swizzle: 512 = 8 * 64 -> each XCD: 4 m-panels x all 16 n (B L2-resident)
    int bid = blockIdx.x;
    int swz = (bid & 7) * 64 + (bid >> 3);
    int m0 = (swz >> 4) * 64, n0 = (swz & 15) * 64;
    const bool doMask = (n0 == 0);
    const bool maskw = doMask && ((wid & 1) == 0);   // wn==0 waves compute rowsums
    const bool mload = doMask && (wid < 2);          // waves 0-1 stage M rows

    // A staging: wave wid stages tile rows wid*8..+8 (1 load/thread)
    const unsigned short* Ag; int sAoff;
    {
        int rl = wid * 8 + lrow;
        Ag = E + (size_t)(m0 + rl) * L_ + ((lseg - rl) & 7) * 8;
        sAoff = (wid * 8) * 64;
    }
    // B staging: wave wid stages tile rows wid*8..+8 (1 load/thread)
    const unsigned short* Bg; int sBoff;
    {
        int rl = wid * 8 + lrow;
        Bg = XmT + (size_t)(n0 + rl) * L_ + ((lseg - rl) & 7) * 8;
        sBoff = 4096 + (wid * 8) * 64;
    }
    // M staging: waves 0-1 stage XmT rows 1024 + wid*8 + lrow (rows >=1028 garbage, discarded)
    const unsigned short* Mg; int sMoff;
    {
        int rl = wid * 8 + lrow;
        Mg = XmT + (size_t)(1024 + rl) * L_ + ((lseg - rl) & 7) * 8;
        sMoff = 8192 + (wid * 8) * 64;
    }

    const int aroff = (wm + lr) * 64, arot = lq + wm + lr;
    int broff[2], brot[2];
#pragma unroll
    for (int j = 0; j < 2; j++) { int br = wn + j * 16 + lr; broff[j] = 4096 + br * 64; brot[j] = lq + br; }
    const int mroff = 8192 + lr * 64, mrot = lq + lr;

    floatx4 acc[2], acc3;
#pragma unroll
    for (int j = 0; j < 2; j++) acc[j] = (floatx4){0.f, 0.f, 0.f, 0.f};
    acc3 = (floatx4){0.f, 0.f, 0.f, 0.f};

    auto stage = [&](unsigned short* base, int k0) {
        async_cp16(base + sAoff, Ag + k0);
        async_cp16(base + sBoff, Bg + k0);
        if (mload) async_cp16(base + sMoff, Mg + k0);
    };
    auto compute = [&](const unsigned short* base) {
#pragma unroll
        for (int s = 0; s < 2; s++) {
            bf16x8 af = *(const bf16x8*)(base + aroff + ((s * 4 + arot) & 7) * 8);
#pragma unroll
            for (int j = 0; j < 2; j++) {
                bf16x8 bfr = *(const bf16x8*)(base + broff[j] + ((s * 4 + brot[j]) & 7) * 8);
                acc[j] = __builtin_amdgcn_mfma_f32_16x16x32_bf16(af, bfr, acc[j], 0, 0, 0);
            }
            if (maskw) {
                bf16x8 bm = *(const bf16x8*)(base + mroff + ((s * 4 + mrot) & 7) * 8);
                acc3 = __builtin_amdgcn_mfma_f32_16x16x32_bf16(af, bm, acc3, 0, 0, 0);
            }
        }
    };

    unsigned short *p0 = sbuf[0], *p1 = sbuf[1], *p2 = sbuf[2];
    stage(p0, 0); stage(p1, 64); stage(p2, 128);
    if (mload) { WAIT_VM(6); } else { WAIT_VM(4); }
    BARRIER();
    for (int p = 0; p < 29; ++p) {
        compute(p0);
        BARRIER();
        stage(p0, (p + 3) << 6);
        if (mload) { WAIT_VM(6); } else { WAIT_VM(4); }
        BARRIER();
        unsigned short* tmp = p0; p0 = p1; p1 = p2; p2 = tmp;
    }
    compute(p0); BARRIER();              // step 29
    if (mload) { WAIT_VM(3); } else { WAIT_VM(2); }
    BARRIER();
    compute(p1); BARRIER();              // step 30
    WAIT_VM(0); BARRIER();
    compute(p2);                         // step 31

#pragma unroll
    for (int j = 0; j < 2; j++)
#pragma unroll
        for (int r = 0; r < 4; r++) {
            int row = m0 + wm + lq * 4 + r;
            int col = n0 + wn + j * 16 + lr;
            Cb[(size_t)row * 1024 + col] = f2bf(acc[j][r]);
        }
    if (maskw && lr < 4) {
#pragma unroll
        for (int r = 0; r < 4; r++) {
            int row = m0 + wm + lq * 4 + r;
            rs[(size_t)row * 4 + lr] = acc3[r];
        }
    }
}

// ---------------- k_ffn v3: producer-consumer, 512 threads ----------------
__global__ __launch_bounds__(512, 1) void k_ffn(const float* __restrict__ x,
                                                const unsigned short* __restrict__ Cb,
                                                const float* __restrict__ rs,
                                                const unsigned short* __restrict__ W1T,
                                                const unsigned short* __restrict__ W2T,
                                                const float* __restrict__ b1,
                                                const float* __restrict__ b2,
                                                const float* __restrict__ g1, const float* __restrict__ be1,
                                                const float* __restrict__ g2, const float* __restrict__ be2,
                                                float* __restrict__ out) {
    __shared__ __align__(16) unsigned short hA[4 * 32 * 64];        // 16 KB
    __shared__ __align__(16) unsigned short W1b[2][4 * 64 * 64];    // 64 KB
    __shared__ __align__(16) unsigned short W2b[2][4 * 64 * 64];    // 64 KB
    __shared__ __align__(16) unsigned short t1c[2][32 * 72];        // 9 KB
    __shared__ float b1s[1024];                                     // 4 KB
    __shared__ float red[4][32][2];                                 // 1 KB  => 158 KB

    const int t = threadIdx.x, lane = t & 63, wid = t >> 6;
    const bool isG1 = wid < 4;
    const int gw = wid & 3;
    const int lr = lane & 15, lq = lane >> 4;
    const int half = lane >> 5, l32 = lane & 31;
    const int lrow8 = lane >> 3, kk = lane & 7;
    const int m0 = blockIdx.x * 32;

    auto stageW1 = [&](unsigned short* buf, int fc) {
#pragma unroll
        for (int q = 0; q < 8; q++) {
            int kc = q >> 1, sub = q & 1;
            int fl = sub * 32 + gw * 8 + lrow8;
            const unsigned short* src = W1T + (size_t)(fc * 64 + fl) * 256 + kc * 64 + (((kk - fl) & 7) * 8);
            async_cp16(buf + kc * 4096 + sub * 2048 + gw * 512, src);
        }
    };
    auto stageW2 = [&](unsigned short* buf, int fc) {
#pragma unroll
        for (int q = 0; q < 8; q++) {
            int nc = q >> 1, sub = q & 1;
            int nl = sub * 32 + gw * 8 + lrow8;
            const unsigned short* src = W2T + (size_t)(nc * 64 + nl) * 1024 + fc * 64 + (((kk - nl) & 7) * 8);
            async_cp16(buf + nc * 4096 + sub * 2048 + gw * 512, src);
        }
    };

    if (isG1) { stageW1(W1b[0], 0); stageW1(W1b[1], 1); }
    else      { stageW2(W2b[0], 0); stageW2(W2b[1], 1); }

    b1s[t] = b1[t];
    b1s[512 + t] = b1[512 + t];
    float4 g1a = *(const float4*)(g1 + l32 * 8);
    float4 g1b = *(const float4*)(g1 + l32 * 8 + 4);
    float4 be1a = *(const float4*)(be1 + l32 * 8);
    float4 be1b = *(const float4*)(be1 + l32 * 8 + 4);

    // ---- LN1: h[32][256] -> hA (rotate-swizzled), 4 tokens/wave ----
#pragma unroll
    for (int it = 0; it < 2; it++) {
        int tloc = wid * 4 + it * 2 + half;
        int tok = m0 + tloc;
        int bi = tok >> 11, ii = tok & (L_ - 1);
        float rsv = rs[(size_t)ii * 4 + bi];
        float4 xv0 = *(const float4*)(x + (size_t)tok * D_ + l32 * 8);
        float4 xv1 = *(const float4*)(x + (size_t)tok * D_ + l32 * 8 + 4);
        ushortx8 cv = *(const ushortx8*)(Cb + (size_t)ii * 1024 + bi * 256 + l32 * 8);
        float v[8];
        v[0] = xv0.x + bf2f(cv[0]) / rsv; v[1] = xv0.y + bf2f(cv[1]) / rsv;
        v[2] = xv0.z + bf2f(cv[2]) / rsv; v[3] = xv0.w + bf2f(cv[3]) / rsv;
        v[4] = xv1.x + bf2f(cv[4]) / rsv; v[5] = xv1.y + bf2f(cv[5]) / rsv;
        v[6] = xv1.z + bf2f(cv[6]) / rsv; v[7] = xv1.w + bf2f(cv[7]) / rsv;
        float s = 0.f, s2 = 0.f;
#pragma unroll
        for (int k = 0; k < 8; k++) { s += v[k]; s2 += v[k] * v[k]; }
#pragma unroll
        for (int o = 1; o < 32; o <<= 1) { s += __shfl_xor(s, o); s2 += __shfl_xor(s2, o); }
        float mu = s * (1.f / 256.f);
        float var = s2 * (1.f / 256.f) - mu * mu;
        float rq = rsqrtf(var + 1e-5f);
        union { bf16x8 v8; unsigned short u[8]; } hv;
        hv.u[0] = f2bf((v[0] - mu) * rq * g1a.x + be1a.x);
        hv.u[1] = f2bf((v[1] - mu) * rq * g1a.y + be1a.y);
        hv.u[2] = f2bf((v[2] - mu) * rq * g1a.z + be1a.z);
        hv.u[3] = f2bf((v[3] - mu) * rq * g1a.w + be1a.w);
        hv.u[4] = f2bf((v[4] - mu) * rq * g1b.x + be1b.x);
        hv.u[5] = f2bf((v[5] - mu) * rq * g1b.y + be1b.y);
        hv.u[6] = f2bf((v[6] - mu) * rq * g1b.z + be1b.z);
        hv.u[7] = f2bf((v[7] - mu) * rq * g1b.w + be1b.w);
        *(bf16x8*)(hA + (l32 >> 3) * 2048 + tloc * 64 + ((((l32 & 7) + tloc) & 7) * 8)) = hv.v8;
    }
    WAIT_VM(0); WAIT_LGKM(); BARRIER();

    bf16x8 haf[2][8];
    if (isG1) {
#pragma unroll
        for (int i = 0; i < 2; i++)
#pragma unroll
            for (int kc = 0; kc < 4; kc++)
#pragma unroll
                for (int s = 0; s < 2; s++) {
                    int row = i * 16 + lr;
                    haf[i][kc * 2 + s] = *(const bf16x8*)(hA + kc * 2048 + row * 64 + (((s * 4 + lq + row) & 7) * 8));
                }
    }

    floatx4 acc[2][4];
#pragma unroll
    for (int i = 0; i < 2; i++)
#pragma unroll
        for (int j = 0; j < 4; j++) acc[i][j] = (floatx4){0.f, 0.f, 0.f, 0.f};

    const int wcol = gw * 16 + lr;

#pragma unroll 1
    for (int cc = 0; cc <= 16; ++cc) {
        if (cc >= 15) { WAIT_VM(0); } else { WAIT_VM(8); }
        BARRIER();
        if (isG1) {
            if (cc < 16) {
                const unsigned short* w1cur = W1b[cc & 1];
                floatx4 a1[2] = { (floatx4){0.f,0.f,0.f,0.f}, (floatx4){0.f,0.f,0.f,0.f} };
#pragma unroll
                for (int kc = 0; kc < 4; kc++)
#pragma unroll
                    for (int s = 0; s < 2; s++) {
                        bf16x8 bfr = *(const bf16x8*)(w1cur + kc * 4096 + wcol * 64 + (((s * 4 + lq + wcol) & 7) * 8));
                        a1[0] = __builtin_amdgcn_mfma_f32_16x16x32_bf16(haf[0][kc * 2 + s], bfr, a1[0], 0, 0, 0);
                        a1[1] = __builtin_amdgcn_mfma_f32_16x16x32_bf16(haf[1][kc * 2 + s], bfr, a1[1], 0, 0, 0);
                    }
                float bv = b1s[cc * 64 + wcol];
                unsigned short* tc = t1c[cc & 1];
#pragma unroll
                for (int i = 0; i < 2; i++)
#pragma unroll
                    for (int r = 0; r < 4; r++)
                        tc[(i * 16 + lq * 4 + r) * 72 + wcol] = f2bf(fmaxf(a1[i][r] + bv, 0.f));
                WAIT_LGKM();
            }
        } else {
            if (cc >= 1) {
                int d = cc - 1;
                const unsigned short* w2cur = W2b[d & 1];
                const unsigned short* tc = t1c[d & 1];
#pragma unroll
                for (int s = 0; s < 2; s++) {
                    bf16x8 af0 = *(const bf16x8*)(tc + lr * 72 + s * 32 + lq * 8);
                    bf16x8 af1 = *(const bf16x8*)(tc + (16 + lr) * 72 + s * 32 + lq * 8);
#pragma unroll
                    for (int j = 0; j < 4; j++) {
                        int nl = j * 16 + lr;
                        bf16x8 bfr = *(const bf16x8*)(w2cur + gw * 4096 + nl * 64 + (((s * 4 + lq + nl) & 7) * 8));
                        acc[0][j] = __builtin_amdgcn_mfma_f32_16x16x32_bf16(af0, bfr, acc[0][j], 0, 0, 0);
                        acc[1][j] = __builtin_amdgcn_mfma_f32_16x16x32_bf16(af1, bfr, acc[1][j], 0, 0, 0);
                    }
                }
            }
        }
        BARRIER();
        if (isG1) {
            if (cc <= 13) stageW1(W1b[cc & 1], cc + 2);
        } else {
            if (cc >= 1 && cc <= 14) stageW2(W2b[(cc - 1) & 1], cc + 1);
        }
    }

    // ---- LN2 epilogue (G2) ----
    float psum[2][4], psq[2][4];
#pragma unroll
    for (int i = 0; i < 2; i++)
#pragma unroll
        for (int r = 0; r < 4; r++) { psum[i][r] = 0.f; psq[i][r] = 0.f; }
    if (!isG1) {
#pragma unroll
        for (int i = 0; i < 2; i++)
#pragma unroll
            for (int j = 0; j < 4; j++) {
                int col = gw * 64 + j * 16 + lr;
                float bv = b2[col];
                int kc = col >> 6, ks = (col >> 3) & 7, ke = col & 7;
#pragma unroll
                for (int r = 0; r < 4; r++) {
                    int row = i * 16 + lq * 4 + r;
                    float hres = bf2f(hA[kc * 2048 + row * 64 + (((ks + row) & 7) * 8) + ke]);
                    float v = acc[i][j][r] + bv + hres;
                    acc[i][j][r] = v;
                    psum[i][r] += v; psq[i][r] += v * v;
                }
            }
#pragma unroll
        for (int o = 1; o < 16; o <<= 1)
#pragma unroll
            for (int i = 0; i < 2; i++)
#pragma unroll
                for (int r = 0; r < 4; r++) { psum[i][r] += __shfl_xor(psum[i][r], o); psq[i][r] += __shfl_xor(psq[i][r], o); }
        if (lr == 0) {
#pragma unroll
            for (int i = 0; i < 2; i++)
#pragma unroll
                for (int r = 0; r < 4; r++) {
                    int lrow = i * 16 + lq * 4 + r;
                    red[gw][lrow][0] = psum[i][r];
                    red[gw][lrow][1] = psq[i][r];
                }
        }
    }
    __syncthreads();
    if (!isG1) {
#pragma unroll
        for (int i = 0; i < 2; i++)
#pragma unroll
            for (int r = 0; r < 4; r++) {
                int lrow = i * 16 + lq * 4 + r;
                float s  = red[0][lrow][0] + red[1][lrow][0] + red[2][lrow][0] + red[3][lrow][0];
                float s2 = red[0][lrow][1] + red[1][lrow][1] + red[2][lrow][1] + red[3][lrow][1];
                float mu = s * (1.f / 256.f);
                float var = s2 * (1.f / 256.f) - mu * mu;
                float rc = rsqrtf(var + 1e-5f);
                int row = m0 + lrow;
#pragma unroll
                for (int j = 0; j < 4; j++) {
                    int col = gw * 64 + j * 16 + lr;
                    out[(size_t)row * 256 + col] = (acc[i][j][r] - mu) * rc * g2[col] + be2[col];
                }
            }
    }
}

extern "C" void kernel_launch(void* const* d_in, const int* in_sizes, int n_in,
                              void* d_out, int out_size, void* d_ws, size_t ws_size,
                              hipStream_t stream) {
    const float* x   = (const float*)d_in[0];
    const int*  mask = (const int*)d_in[1];
    const float* W1  = (const float*)d_in[2];
    const float* b1  = (const float*)d_in[3];
    const float* W2  = (const float*)d_in[4];
    const float* b2  = (const float*)d_in[5];
    const float* g1  = (const float*)d_in[6];
    const float* be1 = (const float*)d_in[7];
    const float* g2  = (const float*)d_in[8];
    const float* be2 = (const float*)d_in[9];
    float* out = (float*)d_out;

    char* w = (char*)d_ws;
    unsigned short* mb_   = (unsigned short*)w;  w += 65536 * 2;                 // 128 KB
    unsigned short* E_    = (unsigned short*)w;  w += (size_t)L_ * L_ * 2;       // 8 MB
    unsigned short* XmT_  = (unsigned short*)w;  w += (size_t)1088 * L_ * 2;     // 4.25 MB (rows 0..1039 read)
    unsigned short* W1T_  = (unsigned short*)w;  w += 262144 * 2;                // 512 KB
    unsigned short* W2T_  = (unsigned short*)w;  w += 262144 * 2;                // 512 KB
    unsigned short* Cb_   = (unsigned short*)w;  w += (size_t)L_ * 1024 * 2;     // 4 MB
    float*          rs_   = (float*)w;           w += (size_t)L_ * 4 * 4;        // 32 KB

    k_prep<<<1537, 256, 0, stream>>>(x, W1, W2, mask, mb_, XmT_, W1T_, W2T_);
    k_scores_mfma<<<dim3(32, 16), 256, 0, stream>>>(mb_, E_);
    k_av<<<512, 512, 0, stream>>>(E_, XmT_, Cb_, rs_);
    k_ffn<<<256, 512, 0, stream>>>(x, Cb_, rs_, W1T_, W2T_, b1, b2, g1, be1, g2, be2, out);
}